// Round 3
// baseline (193.360 us; speedup 1.0000x reference)
//
#include <hip/hip_runtime.h>
#include <hip/hip_bf16.h>
#include <stdint.h>

// Problem constants (from reference)
#define BATCH 4096
#define D_X   1024
#define D_Y   512

constexpr float SIGMA_INV = 0.1f;    // 1/10.0
constexpr float EPS_THR   = 46.0f;

constexpr int BM = 128;              // tile M = tile N
constexpr int NT = BATCH / BM;       // 32 tile-rows
constexpr int NBLK = NT * (NT + 1) / 2;  // 528 upper-triangular tiles (528%8==0)

constexpr int XSLOTS = D_X / 8;      // 128 16B-slots (8 bf16) per x row
constexpr int YSLOTS = D_Y / 8;      // 64 slots per y row
constexpr int NSX = D_X / 64;        // 16 X K-steps
constexpr int NS  = NSX + D_Y / 64;  // 24 total K-steps

typedef __bf16 bf16x8 __attribute__((ext_vector_type(8)));
typedef float  f32x4  __attribute__((ext_vector_type(4)));
typedef unsigned short u16x8 __attribute__((ext_vector_type(8)));

__device__ __forceinline__ unsigned short f32_to_bf16_bits(float f) {
    unsigned int u = __builtin_bit_cast(unsigned int, f);
    unsigned int r = (u + 0x7FFFu + ((u >> 16) & 1u)) >> 16;  // RNE
    return (unsigned short)r;
}

// ===========================================================================
// FAST PATH
// ===========================================================================

// ---------------------------------------------------------------------------
// Kernel 1: f32 -> bf16 conversion with PRE-SWIZZLED slot layout + row norms.
// Stored slot s of row r holds original slot (s&~7)|((s&7)^(r&7)) so a LINEAR
// global_load_lds stage yields the XOR-swizzled LDS tile (swizzle-the-source).
// ---------------------------------------------------------------------------
__global__ void __launch_bounds__(192)
convert_kernel(const float* __restrict__ x, const float* __restrict__ y,
               u16x8* __restrict__ xb, u16x8* __restrict__ yb,
               float* __restrict__ sqx, float* __restrict__ sqy) {
    __shared__ float part[2];
    const int row = blockIdx.x;
    const int t   = threadIdx.x;
    const int lane = t & 63;
    const int wid  = t >> 6;

    float ss = 0.f;
    if (t < 128) {
        const float4* p = (const float4*)(x + (size_t)row * D_X + t * 8);
        float4 a = p[0], b = p[1];
        ss = a.x*a.x + a.y*a.y + a.z*a.z + a.w*a.w
           + b.x*b.x + b.y*b.y + b.z*b.z + b.w*b.w;
        u16x8 v;
        v[0] = f32_to_bf16_bits(a.x); v[1] = f32_to_bf16_bits(a.y);
        v[2] = f32_to_bf16_bits(a.z); v[3] = f32_to_bf16_bits(a.w);
        v[4] = f32_to_bf16_bits(b.x); v[5] = f32_to_bf16_bits(b.y);
        v[6] = f32_to_bf16_bits(b.z); v[7] = f32_to_bf16_bits(b.w);
        int s = (t & ~7) | ((t & 7) ^ (row & 7));
        xb[(size_t)row * XSLOTS + s] = v;
    } else {
        int o = t - 128;  // 0..63
        const float4* p = (const float4*)(y + (size_t)row * D_Y + o * 8);
        float4 a = p[0], b = p[1];
        ss = a.x*a.x + a.y*a.y + a.z*a.z + a.w*a.w
           + b.x*b.x + b.y*b.y + b.z*b.z + b.w*b.w;
        u16x8 v;
        v[0] = f32_to_bf16_bits(a.x); v[1] = f32_to_bf16_bits(a.y);
        v[2] = f32_to_bf16_bits(a.z); v[3] = f32_to_bf16_bits(a.w);
        v[4] = f32_to_bf16_bits(b.x); v[5] = f32_to_bf16_bits(b.y);
        v[6] = f32_to_bf16_bits(b.z); v[7] = f32_to_bf16_bits(b.w);
        int s = (o & ~7) | ((o & 7) ^ (row & 7));
        yb[(size_t)row * YSLOTS + s] = v;
    }
#pragma unroll
    for (int off = 32; off > 0; off >>= 1)
        ss += __shfl_down(ss, off, 64);
    if (lane == 0) {
        if (wid < 2) part[wid] = ss;
        else         sqy[row] = ss;
    }
    __syncthreads();
    if (t == 0) sqx[row] = part[0] + part[1];
}

// ---------------------------------------------------------------------------
// Async stage: 128 rows x 8 slots (16 KB) pre-swizzled bf16 panel -> LDS,
// linear dest, 16B global_load_lds.
// ---------------------------------------------------------------------------
__device__ __forceinline__ void stage(const u16x8* __restrict__ src, int rowslots,
                                      int base_row, int kslot0,
                                      u16x8* dst, int tid) {
    const int wid = tid >> 6, lane = tid & 63;
#pragma unroll
    for (int it = 0; it < 4; ++it) {
        int u  = it * 256 + wid * 64;   // wave-uniform LDS slot base
        int ul = u + lane;
        int row = ul >> 3, slot = ul & 7;
        const u16x8* g = src + (size_t)(base_row + row) * rowslots + kslot0 + slot;
        __builtin_amdgcn_global_load_lds(
            (const uint32_t __attribute__((address_space(1)))*)g,
            (uint32_t __attribute__((address_space(3)))*)(dst + u), 16, 0, 0);
    }
}

// One K=64 step: 2 ks x 16 MFMA reading swizzled LDS tiles.
__device__ __forceinline__ void mfma_step(const u16x8* As_, const u16x8* Bs_,
                                          int wr, int wc, int lrow, int kgrp,
                                          f32x4 acc[4][4]) {
#pragma unroll
    for (int ks = 0; ks < 2; ++ks) {
        bf16x8 a[4], b[4];
#pragma unroll
        for (int m = 0; m < 4; ++m) {
            int row  = wr * 64 + m * 16 + lrow;
            int slot = (ks * 4 + kgrp) ^ (row & 7);
            a[m] = __builtin_bit_cast(bf16x8, As_[row * 8 + slot]);
        }
#pragma unroll
        for (int n = 0; n < 4; ++n) {
            int row  = wc * 64 + n * 16 + lrow;
            int slot = (ks * 4 + kgrp) ^ (row & 7);
            b[n] = __builtin_bit_cast(bf16x8, Bs_[row * 8 + slot]);
        }
#pragma unroll
        for (int m = 0; m < 4; ++m)
#pragma unroll
            for (int n = 0; n < 4; ++n)
                acc[m][n] = __builtin_amdgcn_mfma_f32_16x16x32_bf16(
                    a[m], b[n], acc[m][n], 0, 0, 0);
    }
}

// ---------------------------------------------------------------------------
// Kernel 2: fused Gram(x), Gram(y) -> masked heat-kernel loss.
// T3-minimum pipeline: double-buffered LDS, prefetch issued BEFORE compute,
// ONE barrier per K-step. X and Y phases unified into a 24-step pipeline.
// ---------------------------------------------------------------------------
__global__ void __launch_bounds__(256, 2)
graph_loss_bf16(const u16x8* __restrict__ xb, const u16x8* __restrict__ yb,
                const float* __restrict__ sqx, const float* __restrict__ sqy,
                float* __restrict__ out) {
    __shared__ u16x8 As[2][BM * 8];  // 2 x 16 KB swizzled bf16 [128][64]
    __shared__ u16x8 Bs[2][BM * 8];  // 2 x 16 KB
    __shared__ float snxA[BM], snxB[BM], snyA[BM], snyB[BM];
    __shared__ float wsum[4];

    const int tid  = threadIdx.x;
    const int lane = tid & 63;
    const int wid  = tid >> 6;
    const int wr   = wid >> 1;
    const int wc   = wid & 1;
    const int lrow = lane & 15;
    const int kgrp = lane >> 4;

    // T1: chunked XCD swizzle (bijective: NBLK % 8 == 0) -> same-XCD blocks
    // get consecutive triangular indices (shared A panels in private L2).
    int sb = (blockIdx.x & 7) * (NBLK / 8) + (blockIdx.x >> 3);

    // triangular tile mapping
    int t0 = sb, bi = 0;
    while (t0 >= NT - bi) { t0 -= NT - bi; ++bi; }
    const int bj = bi + t0;
    const int iA = bi * BM;
    const int iB = bj * BM;
    const bool diag = (bi == bj);

    if (tid < BM) {
        snxA[tid] = sqx[iA + tid];
        snyA[tid] = sqy[iA + tid];
        snxB[tid] = sqx[iB + tid];
        snyB[tid] = sqy[iB + tid];
    }

    f32x4 accX[4][4] = {};
    f32x4 accY[4][4] = {};

    // ---- prologue: stage step 0 into buffer 0 ----
    stage(xb, XSLOTS, iA, 0, As[0], tid);
    if (!diag) stage(xb, XSLOTS, iB, 0, Bs[0], tid);
    __syncthreads();   // vmcnt(0) drain + barrier: buf0 ready

    int cur = 0;
    for (int t = 0; t < NS; ++t) {
        // 1) issue prefetch of step t+1 into the other buffer (in flight
        //    across the whole compute phase; drained by the syncthreads below)
        int tn = t + 1;
        if (tn < NS) {
            int nxt = cur ^ 1;
            if (tn < NSX) {
                stage(xb, XSLOTS, iA, tn * 8, As[nxt], tid);
                if (!diag) stage(xb, XSLOTS, iB, tn * 8, Bs[nxt], tid);
            } else {
                int kt = tn - NSX;
                stage(yb, YSLOTS, iA, kt * 8, As[nxt], tid);
                if (!diag) stage(yb, YSLOTS, iB, kt * 8, Bs[nxt], tid);
            }
        }
        // 2) compute current step
        const u16x8* Asp = As[cur];
        const u16x8* Bsp = diag ? As[cur] : Bs[cur];
        if (t < NSX) mfma_step(Asp, Bsp, wr, wc, lrow, kgrp, accX);
        else         mfma_step(Asp, Bsp, wr, wc, lrow, kgrp, accY);
        // 3) single barrier: drains prefetch (vmcnt 0) + guards buffer reuse
        __syncthreads();
        cur ^= 1;
    }

    // ---- Epilogue: C/D layout col=lane&15, row=(lane>>4)*4+reg (m89) ----
    float local = 0.f;
#pragma unroll
    for (int m = 0; m < 4; ++m) {
#pragma unroll
        for (int n = 0; n < 4; ++n) {
            int col   = wc * 64 + n * 16 + lrow;
            float sxj = snxB[col];
            float syj = snyB[col];
#pragma unroll
            for (int r = 0; r < 4; ++r) {
                int rowi  = wr * 64 + m * 16 + kgrp * 4 + r;
                float d2x = snxA[rowi] + sxj - 2.f * accX[m][n][r];
                float dxv = sqrtf(fmaxf(d2x, 1e-12f));
                float d2y = snyA[rowi] + syj - 2.f * accY[m][n][r];
                float dyv = sqrtf(fmaxf(d2y, 1e-12f));
                int gi = iA + rowi, gj = iB + col;
                bool keep = (gi != gj) && (dxv <= EPS_THR);
                float contrib = __expf(-dxv * SIGMA_INV) * dyv;
                local += keep ? contrib : 0.f;
            }
        }
    }
    if (!diag) local *= 2.f;

#pragma unroll
    for (int off = 32; off > 0; off >>= 1)
        local += __shfl_down(local, off, 64);
    if (lane == 0) wsum[wid] = local;
    __syncthreads();
    if (tid == 0)
        atomicAdd(out, wsum[0] + wsum[1] + wsum[2] + wsum[3]);
}

// ===========================================================================
// FALLBACK PATH (used only if ws_size is too small)
// ===========================================================================
__global__ void norms_kernel_fb(const float* __restrict__ x,
                                const float* __restrict__ y,
                                float* __restrict__ sqx,
                                float* __restrict__ sqy) {
    int row = blockIdx.x;
    int t   = threadIdx.x;
    const float4* xr = (const float4*)(x + (size_t)row * D_X);
    float sx = 0.f;
#pragma unroll
    for (int i = 0; i < D_X / 4 / 64; ++i) {
        float4 v = xr[t + i * 64];
        sx += v.x * v.x + v.y * v.y + v.z * v.z + v.w * v.w;
    }
    const float4* yr = (const float4*)(y + (size_t)row * D_Y);
    float sy = 0.f;
#pragma unroll
    for (int i = 0; i < D_Y / 4 / 64; ++i) {
        float4 v = yr[t + i * 64];
        sy += v.x * v.x + v.y * v.y + v.z * v.z + v.w * v.w;
    }
#pragma unroll
    for (int off = 32; off > 0; off >>= 1) {
        sx += __shfl_down(sx, off, 64);
        sy += __shfl_down(sy, off, 64);
    }
    if (t == 0) { sqx[row] = sx; sqy[row] = sy; }
}

__device__ __forceinline__ void stage_tile_fb(const float* __restrict__ src, int ld,
                                              int base_row, int k0,
                                              u16x8* __restrict__ dst, int tid) {
#pragma unroll
    for (int it = 0; it < 2; ++it) {
        int u   = tid + it * 256;
        int row = u >> 2;
        int q   = u & 3;
        const float4* p = (const float4*)(src + (size_t)(base_row + row) * ld + k0 + q * 16);
        float4 f0 = p[0], f1 = p[1], f2 = p[2], f3 = p[3];
        u16x8 lo, hi;
        lo[0] = f32_to_bf16_bits(f0.x); lo[1] = f32_to_bf16_bits(f0.y);
        lo[2] = f32_to_bf16_bits(f0.z); lo[3] = f32_to_bf16_bits(f0.w);
        lo[4] = f32_to_bf16_bits(f1.x); lo[5] = f32_to_bf16_bits(f1.y);
        lo[6] = f32_to_bf16_bits(f1.z); lo[7] = f32_to_bf16_bits(f1.w);
        hi[0] = f32_to_bf16_bits(f2.x); hi[1] = f32_to_bf16_bits(f2.y);
        hi[2] = f32_to_bf16_bits(f2.z); hi[3] = f32_to_bf16_bits(f2.w);
        hi[4] = f32_to_bf16_bits(f3.x); hi[5] = f32_to_bf16_bits(f3.y);
        hi[6] = f32_to_bf16_bits(f3.z); hi[7] = f32_to_bf16_bits(f3.w);
        int swz = row & 7;
        dst[row * 8 + ((2 * q) ^ swz)]     = lo;
        dst[row * 8 + ((2 * q + 1) ^ swz)] = hi;
    }
}

__global__ void __launch_bounds__(256, 2)
graph_loss_fb(const float* __restrict__ x, const float* __restrict__ y,
              const float* __restrict__ sqx, const float* __restrict__ sqy,
              float* __restrict__ out) {
    __shared__ u16x8 As[BM * 8];
    __shared__ u16x8 Bs[BM * 8];
    __shared__ float snxA[BM], snxB[BM], snyA[BM], snyB[BM];
    __shared__ float wsum[4];

    const int tid  = threadIdx.x;
    const int lane = tid & 63;
    const int wid  = tid >> 6;
    const int wr   = wid >> 1;
    const int wc   = wid & 1;
    const int lrow = lane & 15;
    const int kgrp = lane >> 4;

    int t = blockIdx.x, bi = 0;
    while (t >= NT - bi) { t -= NT - bi; ++bi; }
    const int bj = bi + t;
    const int iA = bi * BM;
    const int iB = bj * BM;

    if (tid < BM) {
        snxA[tid] = sqx[iA + tid];
        snyA[tid] = sqy[iA + tid];
        snxB[tid] = sqx[iB + tid];
        snyB[tid] = sqy[iB + tid];
    }

    f32x4 accX[4][4] = {};
    f32x4 accY[4][4] = {};

    for (int kt = 0; kt < D_X / 64; ++kt) {
        __syncthreads();
        stage_tile_fb(x, D_X, iA, kt * 64, As, tid);
        stage_tile_fb(x, D_X, iB, kt * 64, Bs, tid);
        __syncthreads();
        mfma_step(As, Bs, wr, wc, lrow, kgrp, accX);
    }
    for (int kt = 0; kt < D_Y / 64; ++kt) {
        __syncthreads();
        stage_tile_fb(y, D_Y, iA, kt * 64, As, tid);
        stage_tile_fb(y, D_Y, iB, kt * 64, Bs, tid);
        __syncthreads();
        mfma_step(As, Bs, wr, wc, lrow, kgrp, accY);
    }

    float local = 0.f;
#pragma unroll
    for (int m = 0; m < 4; ++m) {
#pragma unroll
        for (int n = 0; n < 4; ++n) {
            int col   = wc * 64 + n * 16 + lrow;
            float sxj = snxB[col];
            float syj = snyB[col];
#pragma unroll
            for (int r = 0; r < 4; ++r) {
                int rowi  = wr * 64 + m * 16 + kgrp * 4 + r;
                float d2x = snxA[rowi] + sxj - 2.f * accX[m][n][r];
                float dxv = sqrtf(fmaxf(d2x, 1e-12f));
                float d2y = snyA[rowi] + syj - 2.f * accY[m][n][r];
                float dyv = sqrtf(fmaxf(d2y, 1e-12f));
                int gi = iA + rowi, gj = iB + col;
                bool keep = (gi != gj) && (dxv <= EPS_THR);
                float contrib = __expf(-dxv * SIGMA_INV) * dyv;
                local += keep ? contrib : 0.f;
            }
        }
    }
    if (bi != bj) local *= 2.f;

#pragma unroll
    for (int off = 32; off > 0; off >>= 1)
        local += __shfl_down(local, off, 64);
    if (lane == 0) wsum[wid] = local;
    __syncthreads();
    if (tid == 0)
        atomicAdd(out, wsum[0] + wsum[1] + wsum[2] + wsum[3]);
}

// ===========================================================================
extern "C" void kernel_launch(void* const* d_in, const int* in_sizes, int n_in,
                              void* d_out, int out_size, void* d_ws, size_t ws_size,
                              hipStream_t stream) {
    const float* x = (const float*)d_in[0];
    const float* y = (const float*)d_in[1];
    float* out = (float*)d_out;

    hipMemsetAsync(d_out, 0, sizeof(float) * (size_t)out_size, stream);

    const size_t xb_bytes = (size_t)BATCH * XSLOTS * 16;   // 8 MB
    const size_t yb_bytes = (size_t)BATCH * YSLOTS * 16;   // 4 MB
    const size_t need = xb_bytes + yb_bytes + 2 * (size_t)BATCH * sizeof(float);

    if (ws_size >= need) {
        u16x8* xb  = (u16x8*)d_ws;
        u16x8* yb  = (u16x8*)((char*)d_ws + xb_bytes);
        float* sqx = (float*)((char*)d_ws + xb_bytes + yb_bytes);
        float* sqy = sqx + BATCH;
        convert_kernel<<<BATCH, 192, 0, stream>>>(x, y, xb, yb, sqx, sqy);
        graph_loss_bf16<<<NBLK, 256, 0, stream>>>(xb, yb, sqx, sqy, out);
    } else {
        float* sqx = (float*)d_ws;
        float* sqy = sqx + BATCH;
        norms_kernel_fb<<<BATCH, 64, 0, stream>>>(x, y, sqx, sqy);
        graph_loss_fb<<<NBLK, 256, 0, stream>>>(x, y, sqx, sqy, out);
    }
}

// Round 4
// 75.270 us; speedup vs baseline: 2.5689x; 2.5689x over previous
//
#include <hip/hip_runtime.h>
#include <hip/hip_bf16.h>
#include <stdint.h>

// Problem constants (from reference)
#define BATCH 4096
#define D_X   1024
#define D_Y   512

constexpr float SIGMA_INV = 0.1f;    // 1/10.0
constexpr float EPS_THR   = 46.0f;

constexpr int BM = 128;              // tile M = tile N
constexpr int NT = BATCH / BM;       // 32 tile-rows
constexpr int NBLK = NT * (NT + 1) / 2;  // 528 upper-triangular tiles (528%8==0)

constexpr int XSLOTS = D_X / 8;      // 128 16B-slots (8 bf16) per x row
constexpr int YSLOTS = D_Y / 8;      // 64 slots per y row
constexpr int NSX = D_X / 64;        // 16 X K-steps
constexpr int NSY = D_Y / 64;        // 8  Y K-steps

typedef __bf16 bf16x8 __attribute__((ext_vector_type(8)));
typedef float  f32x4  __attribute__((ext_vector_type(4)));
typedef unsigned short u16x8 __attribute__((ext_vector_type(8)));

__device__ __forceinline__ unsigned short f32_to_bf16_bits(float f) {
    unsigned int u = __builtin_bit_cast(unsigned int, f);
    unsigned int r = (u + 0x7FFFu + ((u >> 16) & 1u)) >> 16;  // RNE
    return (unsigned short)r;
}

// ===========================================================================
// FAST PATH
// ===========================================================================

// ---------------------------------------------------------------------------
// Kernel 1: f32 -> bf16 conversion with PRE-SWIZZLED slot layout + row norms.
// Stored slot s of row r holds original slot (s&~7)|((s&7)^(r&7)) so a LINEAR
// global_load_lds stage yields the XOR-swizzled LDS tile (swizzle-the-source).
// ---------------------------------------------------------------------------
__global__ void __launch_bounds__(192)
convert_kernel(const float* __restrict__ x, const float* __restrict__ y,
               u16x8* __restrict__ xb, u16x8* __restrict__ yb,
               float* __restrict__ sqx, float* __restrict__ sqy) {
    __shared__ float part[2];
    const int row = blockIdx.x;
    const int t   = threadIdx.x;
    const int lane = t & 63;
    const int wid  = t >> 6;

    float ss = 0.f;
    if (t < 128) {
        const float4* p = (const float4*)(x + (size_t)row * D_X + t * 8);
        float4 a = p[0], b = p[1];
        ss = a.x*a.x + a.y*a.y + a.z*a.z + a.w*a.w
           + b.x*b.x + b.y*b.y + b.z*b.z + b.w*b.w;
        u16x8 v;
        v[0] = f32_to_bf16_bits(a.x); v[1] = f32_to_bf16_bits(a.y);
        v[2] = f32_to_bf16_bits(a.z); v[3] = f32_to_bf16_bits(a.w);
        v[4] = f32_to_bf16_bits(b.x); v[5] = f32_to_bf16_bits(b.y);
        v[6] = f32_to_bf16_bits(b.z); v[7] = f32_to_bf16_bits(b.w);
        int s = (t & ~7) | ((t & 7) ^ (row & 7));
        xb[(size_t)row * XSLOTS + s] = v;
    } else {
        int o = t - 128;  // 0..63
        const float4* p = (const float4*)(y + (size_t)row * D_Y + o * 8);
        float4 a = p[0], b = p[1];
        ss = a.x*a.x + a.y*a.y + a.z*a.z + a.w*a.w
           + b.x*b.x + b.y*b.y + b.z*b.z + b.w*b.w;
        u16x8 v;
        v[0] = f32_to_bf16_bits(a.x); v[1] = f32_to_bf16_bits(a.y);
        v[2] = f32_to_bf16_bits(a.z); v[3] = f32_to_bf16_bits(a.w);
        v[4] = f32_to_bf16_bits(b.x); v[5] = f32_to_bf16_bits(b.y);
        v[6] = f32_to_bf16_bits(b.z); v[7] = f32_to_bf16_bits(b.w);
        int s = (o & ~7) | ((o & 7) ^ (row & 7));
        yb[(size_t)row * YSLOTS + s] = v;
    }
#pragma unroll
    for (int off = 32; off > 0; off >>= 1)
        ss += __shfl_down(ss, off, 64);
    if (lane == 0) {
        if (wid < 2) part[wid] = ss;
        else         sqy[row] = ss;
    }
    __syncthreads();
    if (t == 0) sqx[row] = part[0] + part[1];
}

// ---------------------------------------------------------------------------
// Async stage: 128 rows x 8 slots (16 KB) pre-swizzled bf16 panel -> LDS,
// linear dest, 16B global_load_lds.
// ---------------------------------------------------------------------------
__device__ __forceinline__ void stage(const u16x8* __restrict__ src, int rowslots,
                                      int base_row, int kslot0,
                                      u16x8* dst, int tid) {
    const int wid = tid >> 6, lane = tid & 63;
#pragma unroll
    for (int it = 0; it < 4; ++it) {
        int u  = it * 256 + wid * 64;   // wave-uniform LDS slot base
        int ul = u + lane;
        int row = ul >> 3, slot = ul & 7;
        const u16x8* g = src + (size_t)(base_row + row) * rowslots + kslot0 + slot;
        __builtin_amdgcn_global_load_lds(
            (const uint32_t __attribute__((address_space(1)))*)g,
            (uint32_t __attribute__((address_space(3)))*)(dst + u), 16, 0, 0);
    }
}

// Load ALL fragments for one K=64 step into registers (issued BEFORE the
// next-step stage so the compiler never orders ds_read after global_load_lds).
__device__ __forceinline__ void load_frags(const u16x8* As_, const u16x8* Bs_,
                                           int wr, int wc, int lrow, int kgrp,
                                           bf16x8 a[2][4], bf16x8 b[2][4]) {
#pragma unroll
    for (int ks = 0; ks < 2; ++ks) {
#pragma unroll
        for (int m = 0; m < 4; ++m) {
            int row  = wr * 64 + m * 16 + lrow;
            int slot = (ks * 4 + kgrp) ^ (row & 7);
            a[ks][m] = __builtin_bit_cast(bf16x8, As_[row * 8 + slot]);
        }
#pragma unroll
        for (int n = 0; n < 4; ++n) {
            int row  = wc * 64 + n * 16 + lrow;
            int slot = (ks * 4 + kgrp) ^ (row & 7);
            b[ks][n] = __builtin_bit_cast(bf16x8, Bs_[row * 8 + slot]);
        }
    }
}

__device__ __forceinline__ void do_mfma(const bf16x8 a[2][4], const bf16x8 b[2][4],
                                        f32x4 acc[4][4]) {
#pragma unroll
    for (int ks = 0; ks < 2; ++ks)
#pragma unroll
        for (int m = 0; m < 4; ++m)
#pragma unroll
            for (int n = 0; n < 4; ++n)
                acc[m][n] = __builtin_amdgcn_mfma_f32_16x16x32_bf16(
                    a[ks][m], b[ks][n], acc[m][n], 0, 0, 0);
}

// ---------------------------------------------------------------------------
// Kernel 2: fused Gram(x), Gram(y) -> masked heat-kernel loss.
// Double-buffered, ONE barrier per K-step, compile-time buffer ping-pong
// (x2 unrolled bodies), ds_reads issued BEFORE next-step global_load_lds.
// ---------------------------------------------------------------------------
__global__ void __launch_bounds__(256, 2)
graph_loss_bf16(const u16x8* __restrict__ xb, const u16x8* __restrict__ yb,
                const float* __restrict__ sqx, const float* __restrict__ sqy,
                float* __restrict__ out) {
    __shared__ u16x8 As0[BM * 8], As1[BM * 8];   // 2 x 16 KB (A tile dbuf)
    __shared__ u16x8 Bs0[BM * 8], Bs1[BM * 8];   // 2 x 16 KB (B tile dbuf)
    __shared__ float snxA[BM], snxB[BM], snyA[BM], snyB[BM];
    __shared__ float wsum[4];

    const int tid  = threadIdx.x;
    const int lane = tid & 63;
    const int wid  = tid >> 6;
    const int wr   = wid >> 1;
    const int wc   = wid & 1;
    const int lrow = lane & 15;
    const int kgrp = lane >> 4;

    // T1: chunked XCD swizzle (bijective: NBLK % 8 == 0).
    int sb = (blockIdx.x & 7) * (NBLK / 8) + (blockIdx.x >> 3);

    // triangular tile mapping
    int t0 = sb, bi = 0;
    while (t0 >= NT - bi) { t0 -= NT - bi; ++bi; }
    const int bj = bi + t0;
    const int iA = bi * BM;
    const int iB = bj * BM;
    const bool diag = (bi == bj);

    if (tid < BM) {
        snxA[tid] = sqx[iA + tid];
        snyA[tid] = sqy[iA + tid];
        snxB[tid] = sqx[iB + tid];
        snyB[tid] = sqy[iB + tid];
    }

    f32x4 accX[4][4] = {};
    f32x4 accY[4][4] = {};
    const u16x8* Bp0 = diag ? As0 : Bs0;   // wave-uniform select, compile-safe
    const u16x8* Bp1 = diag ? As1 : Bs1;

    bf16x8 a[2][4], b[2][4];

    // ---- prologue: stage X step 0 into buf0 ----
    stage(xb, XSLOTS, iA, 0, As0, tid);
    if (!diag) stage(xb, XSLOTS, iB, 0, Bs0, tid);
    __syncthreads();   // vmcnt(0) drain + barrier: buf0 ready

    // ---- X phase: 16 steps, unrolled x2 for static buffer ping-pong ----
    for (int kt = 0; kt < NSX; kt += 2) {
        // even step: read buf0, prefetch step kt+1 -> buf1 (kt+1 < NSX always)
        load_frags(As0, Bp0, wr, wc, lrow, kgrp, a, b);
        stage(xb, XSLOTS, iA, (kt + 1) * 8, As1, tid);
        if (!diag) stage(xb, XSLOTS, iB, (kt + 1) * 8, Bs1, tid);
        do_mfma(a, b, accX);
        __syncthreads();
        // odd step: read buf1, prefetch step kt+2 -> buf0 (or Y step 0)
        load_frags(As1, Bp1, wr, wc, lrow, kgrp, a, b);
        if (kt + 2 < NSX) {
            stage(xb, XSLOTS, iA, (kt + 2) * 8, As0, tid);
            if (!diag) stage(xb, XSLOTS, iB, (kt + 2) * 8, Bs0, tid);
        } else {
            stage(yb, YSLOTS, iA, 0, As0, tid);
            if (!diag) stage(yb, YSLOTS, iB, 0, Bs0, tid);
        }
        do_mfma(a, b, accX);
        __syncthreads();
    }

    // ---- Y phase: 8 steps, buf0 holds Y step 0 ----
    for (int kt = 0; kt < NSY; kt += 2) {
        // even step: read buf0, prefetch step kt+1 -> buf1 (kt+1 < NSY always)
        load_frags(As0, Bp0, wr, wc, lrow, kgrp, a, b);
        stage(yb, YSLOTS, iA, (kt + 1) * 8, As1, tid);
        if (!diag) stage(yb, YSLOTS, iB, (kt + 1) * 8, Bs1, tid);
        do_mfma(a, b, accY);
        __syncthreads();
        // odd step: read buf1, prefetch step kt+2 -> buf0
        load_frags(As1, Bp1, wr, wc, lrow, kgrp, a, b);
        if (kt + 2 < NSY) {
            stage(yb, YSLOTS, iA, (kt + 2) * 8, As0, tid);
            if (!diag) stage(yb, YSLOTS, iB, (kt + 2) * 8, Bs0, tid);
        }
        do_mfma(a, b, accY);
        __syncthreads();
    }

    // ---- Epilogue: C/D layout col=lane&15, row=(lane>>4)*4+reg (m89) ----
    float local = 0.f;
#pragma unroll
    for (int m = 0; m < 4; ++m) {
#pragma unroll
        for (int n = 0; n < 4; ++n) {
            int col   = wc * 64 + n * 16 + lrow;
            float sxj = snxB[col];
            float syj = snyB[col];
#pragma unroll
            for (int r = 0; r < 4; ++r) {
                int rowi  = wr * 64 + m * 16 + kgrp * 4 + r;
                float d2x = snxA[rowi] + sxj - 2.f * accX[m][n][r];
                float dxv = sqrtf(fmaxf(d2x, 1e-12f));
                float d2y = snyA[rowi] + syj - 2.f * accY[m][n][r];
                float dyv = sqrtf(fmaxf(d2y, 1e-12f));
                int gi = iA + rowi, gj = iB + col;
                bool keep = (gi != gj) && (dxv <= EPS_THR);
                float contrib = __expf(-dxv * SIGMA_INV) * dyv;
                local += keep ? contrib : 0.f;
            }
        }
    }
    if (!diag) local *= 2.f;

#pragma unroll
    for (int off = 32; off > 0; off >>= 1)
        local += __shfl_down(local, off, 64);
    if (lane == 0) wsum[wid] = local;
    __syncthreads();
    if (tid == 0)
        atomicAdd(out, wsum[0] + wsum[1] + wsum[2] + wsum[3]);
}

// ===========================================================================
// FALLBACK PATH (used only if ws_size is too small)
// ===========================================================================
__global__ void norms_kernel_fb(const float* __restrict__ x,
                                const float* __restrict__ y,
                                float* __restrict__ sqx,
                                float* __restrict__ sqy) {
    int row = blockIdx.x;
    int t   = threadIdx.x;
    const float4* xr = (const float4*)(x + (size_t)row * D_X);
    float sx = 0.f;
#pragma unroll
    for (int i = 0; i < D_X / 4 / 64; ++i) {
        float4 v = xr[t + i * 64];
        sx += v.x * v.x + v.y * v.y + v.z * v.z + v.w * v.w;
    }
    const float4* yr = (const float4*)(y + (size_t)row * D_Y);
    float sy = 0.f;
#pragma unroll
    for (int i = 0; i < D_Y / 4 / 64; ++i) {
        float4 v = yr[t + i * 64];
        sy += v.x * v.x + v.y * v.y + v.z * v.z + v.w * v.w;
    }
#pragma unroll
    for (int off = 32; off > 0; off >>= 1) {
        sx += __shfl_down(sx, off, 64);
        sy += __shfl_down(sy, off, 64);
    }
    if (t == 0) { sqx[row] = sx; sqy[row] = sy; }
}

__device__ __forceinline__ void stage_tile_fb(const float* __restrict__ src, int ld,
                                              int base_row, int k0,
                                              u16x8* __restrict__ dst, int tid) {
#pragma unroll
    for (int it = 0; it < 2; ++it) {
        int u   = tid + it * 256;
        int row = u >> 2;
        int q   = u & 3;
        const float4* p = (const float4*)(src + (size_t)(base_row + row) * ld + k0 + q * 16);
        float4 f0 = p[0], f1 = p[1], f2 = p[2], f3 = p[3];
        u16x8 lo, hi;
        lo[0] = f32_to_bf16_bits(f0.x); lo[1] = f32_to_bf16_bits(f0.y);
        lo[2] = f32_to_bf16_bits(f0.z); lo[3] = f32_to_bf16_bits(f0.w);
        lo[4] = f32_to_bf16_bits(f1.x); lo[5] = f32_to_bf16_bits(f1.y);
        lo[6] = f32_to_bf16_bits(f1.z); lo[7] = f32_to_bf16_bits(f1.w);
        hi[0] = f32_to_bf16_bits(f2.x); hi[1] = f32_to_bf16_bits(f2.y);
        hi[2] = f32_to_bf16_bits(f2.z); hi[3] = f32_to_bf16_bits(f2.w);
        hi[4] = f32_to_bf16_bits(f3.x); hi[5] = f32_to_bf16_bits(f3.y);
        hi[6] = f32_to_bf16_bits(f3.z); hi[7] = f32_to_bf16_bits(f3.w);
        int swz = row & 7;
        dst[row * 8 + ((2 * q) ^ swz)]     = lo;
        dst[row * 8 + ((2 * q + 1) ^ swz)] = hi;
    }
}

__global__ void __launch_bounds__(256, 2)
graph_loss_fb(const float* __restrict__ x, const float* __restrict__ y,
              const float* __restrict__ sqx, const float* __restrict__ sqy,
              float* __restrict__ out) {
    __shared__ u16x8 As[BM * 8];
    __shared__ u16x8 Bs[BM * 8];
    __shared__ float snxA[BM], snxB[BM], snyA[BM], snyB[BM];
    __shared__ float wsum[4];

    const int tid  = threadIdx.x;
    const int lane = tid & 63;
    const int wid  = tid >> 6;
    const int wr   = wid >> 1;
    const int wc   = wid & 1;
    const int lrow = lane & 15;
    const int kgrp = lane >> 4;

    int t = blockIdx.x, bi = 0;
    while (t >= NT - bi) { t -= NT - bi; ++bi; }
    const int bj = bi + t;
    const int iA = bi * BM;
    const int iB = bj * BM;

    if (tid < BM) {
        snxA[tid] = sqx[iA + tid];
        snyA[tid] = sqy[iA + tid];
        snxB[tid] = sqx[iB + tid];
        snyB[tid] = sqy[iB + tid];
    }

    f32x4 accX[4][4] = {};
    f32x4 accY[4][4] = {};
    bf16x8 a[2][4], b[2][4];

    for (int kt = 0; kt < NSX; ++kt) {
        __syncthreads();
        stage_tile_fb(x, D_X, iA, kt * 64, As, tid);
        stage_tile_fb(x, D_X, iB, kt * 64, Bs, tid);
        __syncthreads();
        load_frags(As, Bs, wr, wc, lrow, kgrp, a, b);
        do_mfma(a, b, accX);
    }
    for (int kt = 0; kt < NSY; ++kt) {
        __syncthreads();
        stage_tile_fb(y, D_Y, iA, kt * 64, As, tid);
        stage_tile_fb(y, D_Y, iB, kt * 64, Bs, tid);
        __syncthreads();
        load_frags(As, Bs, wr, wc, lrow, kgrp, a, b);
        do_mfma(a, b, accY);
    }

    float local = 0.f;
#pragma unroll
    for (int m = 0; m < 4; ++m) {
#pragma unroll
        for (int n = 0; n < 4; ++n) {
            int col   = wc * 64 + n * 16 + lrow;
            float sxj = snxB[col];
            float syj = snyB[col];
#pragma unroll
            for (int r = 0; r < 4; ++r) {
                int rowi  = wr * 64 + m * 16 + kgrp * 4 + r;
                float d2x = snxA[rowi] + sxj - 2.f * accX[m][n][r];
                float dxv = sqrtf(fmaxf(d2x, 1e-12f));
                float d2y = snyA[rowi] + syj - 2.f * accY[m][n][r];
                float dyv = sqrtf(fmaxf(d2y, 1e-12f));
                int gi = iA + rowi, gj = iB + col;
                bool keep = (gi != gj) && (dxv <= EPS_THR);
                float contrib = __expf(-dxv * SIGMA_INV) * dyv;
                local += keep ? contrib : 0.f;
            }
        }
    }
    if (bi != bj) local *= 2.f;

#pragma unroll
    for (int off = 32; off > 0; off >>= 1)
        local += __shfl_down(local, off, 64);
    if (lane == 0) wsum[wid] = local;
    __syncthreads();
    if (tid == 0)
        atomicAdd(out, wsum[0] + wsum[1] + wsum[2] + wsum[3]);
}

// ===========================================================================
extern "C" void kernel_launch(void* const* d_in, const int* in_sizes, int n_in,
                              void* d_out, int out_size, void* d_ws, size_t ws_size,
                              hipStream_t stream) {
    const float* x = (const float*)d_in[0];
    const float* y = (const float*)d_in[1];
    float* out = (float*)d_out;

    hipMemsetAsync(d_out, 0, sizeof(float) * (size_t)out_size, stream);

    const size_t xb_bytes = (size_t)BATCH * XSLOTS * 16;   // 8 MB
    const size_t yb_bytes = (size_t)BATCH * YSLOTS * 16;   // 4 MB
    const size_t need = xb_bytes + yb_bytes + 2 * (size_t)BATCH * sizeof(float);

    if (ws_size >= need) {
        u16x8* xb  = (u16x8*)d_ws;
        u16x8* yb  = (u16x8*)((char*)d_ws + xb_bytes);
        float* sqx = (float*)((char*)d_ws + xb_bytes + yb_bytes);
        float* sqy = sqx + BATCH;
        convert_kernel<<<BATCH, 192, 0, stream>>>(x, y, xb, yb, sqx, sqy);
        graph_loss_bf16<<<NBLK, 256, 0, stream>>>(xb, yb, sqx, sqy, out);
    } else {
        float* sqx = (float*)d_ws;
        float* sqy = sqx + BATCH;
        norms_kernel_fb<<<BATCH, 64, 0, stream>>>(x, y, sqx, sqy);
        graph_loss_fb<<<NBLK, 256, 0, stream>>>(x, y, sqx, sqy, out);
    }
}

// Round 5
// 73.518 us; speedup vs baseline: 2.6301x; 1.0238x over previous
//
#include <hip/hip_runtime.h>
#include <hip/hip_bf16.h>
#include <stdint.h>

// Problem constants (from reference)
#define BATCH 4096
#define D_X   1024
#define D_Y   512

constexpr float SIGMA_INV = 0.1f;    // 1/10.0
constexpr float EPS_THR   = 46.0f;

constexpr int BM = 128;              // tile M = tile N
constexpr int NT = BATCH / BM;       // 32 tile-rows
constexpr int NBLK = NT * (NT + 1) / 2;  // 528 upper-triangular tiles (528%8==0)

constexpr int XSLOTS = D_X / 8;      // 128 16B-slots (8 bf16) per x row
constexpr int YSLOTS = D_Y / 8;      // 64 slots per y row
constexpr int NSTEPX = D_X / 32;     // 32 X K-steps (BK=32)
constexpr int NSTEP  = NSTEPX + D_Y / 32;  // 48 total K-steps

typedef __bf16 bf16x8 __attribute__((ext_vector_type(8)));
typedef float  f32x4  __attribute__((ext_vector_type(4)));
typedef unsigned short u16x8 __attribute__((ext_vector_type(8)));

__device__ __forceinline__ unsigned short f32_to_bf16_bits(float f) {
    unsigned int u = __builtin_bit_cast(unsigned int, f);
    unsigned int r = (u + 0x7FFFu + ((u >> 16) & 1u)) >> 16;  // RNE
    return (unsigned short)r;
}

// ===========================================================================
// FAST PATH
// ===========================================================================

// ---------------------------------------------------------------------------
// Kernel 1: f32 -> bf16 (LINEAR slot layout) + row norms.
// ---------------------------------------------------------------------------
__global__ void __launch_bounds__(192)
convert_kernel(const float* __restrict__ x, const float* __restrict__ y,
               u16x8* __restrict__ xb, u16x8* __restrict__ yb,
               float* __restrict__ sqx, float* __restrict__ sqy) {
    __shared__ float part[2];
    const int row = blockIdx.x;
    const int t   = threadIdx.x;
    const int lane = t & 63;
    const int wid  = t >> 6;

    float ss = 0.f;
    if (t < 128) {
        const float4* p = (const float4*)(x + (size_t)row * D_X + t * 8);
        float4 a = p[0], b = p[1];
        ss = a.x*a.x + a.y*a.y + a.z*a.z + a.w*a.w
           + b.x*b.x + b.y*b.y + b.z*b.z + b.w*b.w;
        u16x8 v;
        v[0] = f32_to_bf16_bits(a.x); v[1] = f32_to_bf16_bits(a.y);
        v[2] = f32_to_bf16_bits(a.z); v[3] = f32_to_bf16_bits(a.w);
        v[4] = f32_to_bf16_bits(b.x); v[5] = f32_to_bf16_bits(b.y);
        v[6] = f32_to_bf16_bits(b.z); v[7] = f32_to_bf16_bits(b.w);
        xb[(size_t)row * XSLOTS + t] = v;
    } else {
        int o = t - 128;  // 0..63
        const float4* p = (const float4*)(y + (size_t)row * D_Y + o * 8);
        float4 a = p[0], b = p[1];
        ss = a.x*a.x + a.y*a.y + a.z*a.z + a.w*a.w
           + b.x*b.x + b.y*b.y + b.z*b.z + b.w*b.w;
        u16x8 v;
        v[0] = f32_to_bf16_bits(a.x); v[1] = f32_to_bf16_bits(a.y);
        v[2] = f32_to_bf16_bits(a.z); v[3] = f32_to_bf16_bits(a.w);
        v[4] = f32_to_bf16_bits(b.x); v[5] = f32_to_bf16_bits(b.y);
        v[6] = f32_to_bf16_bits(b.z); v[7] = f32_to_bf16_bits(b.w);
        yb[(size_t)row * YSLOTS + o] = v;
    }
#pragma unroll
    for (int off = 32; off > 0; off >>= 1)
        ss += __shfl_down(ss, off, 64);
    if (lane == 0) {
        if (wid < 2) part[wid] = ss;
        else         sqy[row] = ss;
    }
    __syncthreads();
    if (t == 0) sqx[row] = part[0] + part[1];
}

// ---------------------------------------------------------------------------
// Issue one K=32 step's staging: [128 rows][8 slots] combined A|B tile, 16 KB.
// Stored slot st of row r holds: logical lg = st ^ (r&7);  lg<4 -> A slot
// (k0+lg) of row iA+r,  lg>=4 -> B slot (k0+lg-4) of row iB+r.
// LDS dest is LINEAR (wave-uniform base + lane*16); the swizzle lives in the
// per-lane GLOBAL source address (rule #21: inverse-swz source + swz read).
// 4 global_load_lds instructions per thread -> 4 vmcnt units per step batch.
// ---------------------------------------------------------------------------
__device__ __forceinline__ void issue_stage(int s,
                                            const u16x8* __restrict__ xb,
                                            const u16x8* __restrict__ yb,
                                            int iA, int iB,
                                            u16x8* dst, int tid) {
    const int wid = tid >> 6, lane = tid & 63;
    const u16x8* src; int rs, k0;
    if (s < NSTEPX) { src = xb; rs = XSLOTS; k0 = s * 4; }
    else            { src = yb; rs = YSLOTS; k0 = (s - NSTEPX) * 4; }
#pragma unroll
    for (int it = 0; it < 4; ++it) {
        int u   = it * 256 + wid * 64;   // wave-uniform LDS slot base
        int ul  = u + lane;
        int row = ul >> 3;
        int st  = ul & 7;
        int lg  = st ^ (row & 7);
        int grow  = (lg < 4 ? iA : iB) + row;
        int gslot = k0 + (lg & 3);
        const u16x8* g = src + (size_t)grow * rs + gslot;
        __builtin_amdgcn_global_load_lds(
            (const uint32_t __attribute__((address_space(1)))*)g,
            (uint32_t __attribute__((address_space(3)))*)(dst + u), 16, 0, 0);
    }
}

// Read the 8 fragments of one K=32 step (A logical slots 0-3, B slots 4-7).
__device__ __forceinline__ void read_frags32(const u16x8* B_, int wr, int wc,
                                             int lrow, int kgrp,
                                             bf16x8 a[4], bf16x8 b[4]) {
#pragma unroll
    for (int m = 0; m < 4; ++m) {
        int row = wr * 64 + m * 16 + lrow;
        int st  = kgrp ^ (row & 7);
        a[m] = __builtin_bit_cast(bf16x8, B_[row * 8 + st]);
    }
#pragma unroll
    for (int n = 0; n < 4; ++n) {
        int row = wc * 64 + n * 16 + lrow;
        int st  = (4 + kgrp) ^ (row & 7);
        b[n] = __builtin_bit_cast(bf16x8, B_[row * 8 + st]);
    }
}

__device__ __forceinline__ void mfma16(const bf16x8 a[4], const bf16x8 b[4],
                                       f32x4 acc[4][4]) {
#pragma unroll
    for (int m = 0; m < 4; ++m)
#pragma unroll
        for (int n = 0; n < 4; ++n)
            acc[m][n] = __builtin_amdgcn_mfma_f32_16x16x32_bf16(
                a[m], b[n], acc[m][n], 0, 0, 0);
}

// One pipeline step: counted vmcnt (NEVER 0 in steady state) + raw barrier.
// RD = buffer holding step T's tile; WR = buffer for step T+3's staging.
#define PIPE_STEP(RD, T, WR, ACC, W)                                      \
    {                                                                     \
        asm volatile("s_waitcnt vmcnt(" #W ")" ::: "memory");             \
        __builtin_amdgcn_s_barrier();                                     \
        bf16x8 fa[4], fb[4];                                              \
        read_frags32(RD, wr, wc, lrow, kgrp, fa, fb);                     \
        issue_stage((T) + 3, xb, yb, iA, iB, WR, tid);                    \
        mfma16(fa, fb, ACC);                                              \
    }
#define PIPE_STEP_NOISSUE(RD, ACC, W)                                     \
    {                                                                     \
        asm volatile("s_waitcnt vmcnt(" #W ")" ::: "memory");             \
        __builtin_amdgcn_s_barrier();                                     \
        bf16x8 fa[4], fb[4];                                              \
        read_frags32(RD, wr, wc, lrow, kgrp, fa, fb);                     \
        mfma16(fa, fb, ACC);                                              \
    }

// ---------------------------------------------------------------------------
// Kernel 2: fused Gram(x), Gram(y) -> masked heat-kernel loss.
// Depth-3 software pipeline: 4 cyclic 16KB step-buffers, counted vmcnt(8),
// one raw barrier per step. Diag blocks stage B redundantly (uniform counts).
// ---------------------------------------------------------------------------
__global__ void __launch_bounds__(256, 2)
graph_loss_bf16(const u16x8* __restrict__ xb, const u16x8* __restrict__ yb,
                const float* __restrict__ sqx, const float* __restrict__ sqy,
                float* __restrict__ out) {
    __shared__ u16x8 buf0[1024], buf1[1024], buf2[1024], buf3[1024];  // 64 KB
    __shared__ float snxA[BM], snxB[BM], snyA[BM], snyB[BM];
    __shared__ float wsum[4];

    const int tid  = threadIdx.x;
    const int lane = tid & 63;
    const int wid  = tid >> 6;
    const int wr   = wid >> 1;
    const int wc   = wid & 1;
    const int lrow = lane & 15;
    const int kgrp = lane >> 4;

    // T1: chunked XCD swizzle (bijective: NBLK % 8 == 0).
    int sb = (blockIdx.x & 7) * (NBLK / 8) + (blockIdx.x >> 3);

    // triangular tile mapping
    int t0 = sb, bi = 0;
    while (t0 >= NT - bi) { t0 -= NT - bi; ++bi; }
    const int bj = bi + t0;
    const int iA = bi * BM;
    const int iB = bj * BM;
    const bool diag = (bi == bj);

    if (tid < BM) {
        snxA[tid] = sqx[iA + tid];
        snyA[tid] = sqy[iA + tid];
        snxB[tid] = sqx[iB + tid];
        snyB[tid] = sqy[iB + tid];
    }

    f32x4 accX[4][4] = {};
    f32x4 accY[4][4] = {};

    // ---- prologue: pre-issue steps 0,1,2; full drain once ----
    issue_stage(0, xb, yb, iA, iB, buf0, tid);
    issue_stage(1, xb, yb, iA, iB, buf1, tid);
    issue_stage(2, xb, yb, iA, iB, buf2, tid);
    __syncthreads();   // drains vmcnt(0): steps 0-2 resident; norms visible

    // ---- X phase: steps 0..31 (accX). Issues reach step 34 (Y ok). ----
    for (int i = 0; i < 8; ++i) {
        int t = i * 4;
        PIPE_STEP(buf0, t + 0, buf3, accX, 8);
        PIPE_STEP(buf1, t + 1, buf0, accX, 8);
        PIPE_STEP(buf2, t + 2, buf1, accX, 8);
        PIPE_STEP(buf3, t + 3, buf2, accX, 8);
    }
    // ---- Y phase: steps 32..43 (accY). Issues reach step 46. ----
    for (int i = 8; i < 11; ++i) {
        int t = i * 4;
        PIPE_STEP(buf0, t + 0, buf3, accY, 8);
        PIPE_STEP(buf1, t + 1, buf0, accY, 8);
        PIPE_STEP(buf2, t + 2, buf1, accY, 8);
        PIPE_STEP(buf3, t + 3, buf2, accY, 8);
    }
    // ---- peeled tail: steps 44..47; drain counts 8,8,4,0 ----
    PIPE_STEP(buf0, 44, buf3, accY, 8);      // issues step 47
    PIPE_STEP_NOISSUE(buf1, accY, 8);        // step 45 (46,47 in flight)
    PIPE_STEP_NOISSUE(buf2, accY, 4);        // step 46 (47 in flight)
    PIPE_STEP_NOISSUE(buf3, accY, 0);        // step 47

    // ---- Epilogue: C/D layout col=lane&15, row=(lane>>4)*4+reg (m89) ----
    float local = 0.f;
#pragma unroll
    for (int m = 0; m < 4; ++m) {
#pragma unroll
        for (int n = 0; n < 4; ++n) {
            int col   = wc * 64 + n * 16 + lrow;
            float sxj = snxB[col];
            float syj = snyB[col];
#pragma unroll
            for (int r = 0; r < 4; ++r) {
                int rowi  = wr * 64 + m * 16 + kgrp * 4 + r;
                float d2x = snxA[rowi] + sxj - 2.f * accX[m][n][r];
                float dxv = sqrtf(fmaxf(d2x, 1e-12f));
                float d2y = snyA[rowi] + syj - 2.f * accY[m][n][r];
                float dyv = sqrtf(fmaxf(d2y, 1e-12f));
                int gi = iA + rowi, gj = iB + col;
                bool keep = (gi != gj) && (dxv <= EPS_THR);
                float contrib = __expf(-dxv * SIGMA_INV) * dyv;
                local += keep ? contrib : 0.f;
            }
        }
    }
    if (!diag) local *= 2.f;

#pragma unroll
    for (int off = 32; off > 0; off >>= 1)
        local += __shfl_down(local, off, 64);
    if (lane == 0) wsum[wid] = local;
    __syncthreads();
    if (tid == 0)
        atomicAdd(out, wsum[0] + wsum[1] + wsum[2] + wsum[3]);
}

// ===========================================================================
// FALLBACK PATH (used only if ws_size is too small) — round-2 structure.
// ===========================================================================
__global__ void norms_kernel_fb(const float* __restrict__ x,
                                const float* __restrict__ y,
                                float* __restrict__ sqx,
                                float* __restrict__ sqy) {
    int row = blockIdx.x;
    int t   = threadIdx.x;
    const float4* xr = (const float4*)(x + (size_t)row * D_X);
    float sx = 0.f;
#pragma unroll
    for (int i = 0; i < D_X / 4 / 64; ++i) {
        float4 v = xr[t + i * 64];
        sx += v.x * v.x + v.y * v.y + v.z * v.z + v.w * v.w;
    }
    const float4* yr = (const float4*)(y + (size_t)row * D_Y);
    float sy = 0.f;
#pragma unroll
    for (int i = 0; i < D_Y / 4 / 64; ++i) {
        float4 v = yr[t + i * 64];
        sy += v.x * v.x + v.y * v.y + v.z * v.z + v.w * v.w;
    }
#pragma unroll
    for (int off = 32; off > 0; off >>= 1) {
        sx += __shfl_down(sx, off, 64);
        sy += __shfl_down(sy, off, 64);
    }
    if (t == 0) { sqx[row] = sx; sqy[row] = sy; }
}

__device__ __forceinline__ void stage_tile_fb(const float* __restrict__ src, int ld,
                                              int base_row, int k0,
                                              u16x8* __restrict__ dst, int tid) {
#pragma unroll
    for (int it = 0; it < 2; ++it) {
        int u   = tid + it * 256;
        int row = u >> 2;
        int q   = u & 3;
        const float4* p = (const float4*)(src + (size_t)(base_row + row) * ld + k0 + q * 16);
        float4 f0 = p[0], f1 = p[1], f2 = p[2], f3 = p[3];
        u16x8 lo, hi;
        lo[0] = f32_to_bf16_bits(f0.x); lo[1] = f32_to_bf16_bits(f0.y);
        lo[2] = f32_to_bf16_bits(f0.z); lo[3] = f32_to_bf16_bits(f0.w);
        lo[4] = f32_to_bf16_bits(f1.x); lo[5] = f32_to_bf16_bits(f1.y);
        lo[6] = f32_to_bf16_bits(f1.z); lo[7] = f32_to_bf16_bits(f1.w);
        hi[0] = f32_to_bf16_bits(f2.x); hi[1] = f32_to_bf16_bits(f2.y);
        hi[2] = f32_to_bf16_bits(f2.z); hi[3] = f32_to_bf16_bits(f2.w);
        hi[4] = f32_to_bf16_bits(f3.x); hi[5] = f32_to_bf16_bits(f3.y);
        hi[6] = f32_to_bf16_bits(f3.z); hi[7] = f32_to_bf16_bits(f3.w);
        int swz = row & 7;
        dst[row * 8 + ((2 * q) ^ swz)]     = lo;
        dst[row * 8 + ((2 * q + 1) ^ swz)] = hi;
    }
}

__device__ __forceinline__ void load_frags_fb(const u16x8* As_, const u16x8* Bs_,
                                              int wr, int wc, int lrow, int kgrp,
                                              bf16x8 a[2][4], bf16x8 b[2][4]) {
#pragma unroll
    for (int ks = 0; ks < 2; ++ks) {
#pragma unroll
        for (int m = 0; m < 4; ++m) {
            int row  = wr * 64 + m * 16 + lrow;
            int slot = (ks * 4 + kgrp) ^ (row & 7);
            a[ks][m] = __builtin_bit_cast(bf16x8, As_[row * 8 + slot]);
        }
#pragma unroll
        for (int n = 0; n < 4; ++n) {
            int row  = wc * 64 + n * 16 + lrow;
            int slot = (ks * 4 + kgrp) ^ (row & 7);
            b[ks][n] = __builtin_bit_cast(bf16x8, Bs_[row * 8 + slot]);
        }
    }
}

__global__ void __launch_bounds__(256, 2)
graph_loss_fb(const float* __restrict__ x, const float* __restrict__ y,
              const float* __restrict__ sqx, const float* __restrict__ sqy,
              float* __restrict__ out) {
    __shared__ u16x8 As[BM * 8];
    __shared__ u16x8 Bs[BM * 8];
    __shared__ float snxA[BM], snxB[BM], snyA[BM], snyB[BM];
    __shared__ float wsum[4];

    const int tid  = threadIdx.x;
    const int lane = tid & 63;
    const int wid  = tid >> 6;
    const int wr   = wid >> 1;
    const int wc   = wid & 1;
    const int lrow = lane & 15;
    const int kgrp = lane >> 4;

    int t = blockIdx.x, bi = 0;
    while (t >= NT - bi) { t -= NT - bi; ++bi; }
    const int bj = bi + t;
    const int iA = bi * BM;
    const int iB = bj * BM;

    if (tid < BM) {
        snxA[tid] = sqx[iA + tid];
        snyA[tid] = sqy[iA + tid];
        snxB[tid] = sqx[iB + tid];
        snyB[tid] = sqy[iB + tid];
    }

    f32x4 accX[4][4] = {};
    f32x4 accY[4][4] = {};
    bf16x8 a[2][4], b[2][4];

    for (int kt = 0; kt < D_X / 64; ++kt) {
        __syncthreads();
        stage_tile_fb(x, D_X, iA, kt * 64, As, tid);
        stage_tile_fb(x, D_X, iB, kt * 64, Bs, tid);
        __syncthreads();
        load_frags_fb(As, Bs, wr, wc, lrow, kgrp, a, b);
#pragma unroll
        for (int ks = 0; ks < 2; ++ks) mfma16(a[ks], b[ks], accX);
    }
    for (int kt = 0; kt < D_Y / 64; ++kt) {
        __syncthreads();
        stage_tile_fb(y, D_Y, iA, kt * 64, As, tid);
        stage_tile_fb(y, D_Y, iB, kt * 64, Bs, tid);
        __syncthreads();
        load_frags_fb(As, Bs, wr, wc, lrow, kgrp, a, b);
#pragma unroll
        for (int ks = 0; ks < 2; ++ks) mfma16(a[ks], b[ks], accY);
    }

    float local = 0.f;
#pragma unroll
    for (int m = 0; m < 4; ++m) {
#pragma unroll
        for (int n = 0; n < 4; ++n) {
            int col   = wc * 64 + n * 16 + lrow;
            float sxj = snxB[col];
            float syj = snyB[col];
#pragma unroll
            for (int r = 0; r < 4; ++r) {
                int rowi  = wr * 64 + m * 16 + kgrp * 4 + r;
                float d2x = snxA[rowi] + sxj - 2.f * accX[m][n][r];
                float dxv = sqrtf(fmaxf(d2x, 1e-12f));
                float d2y = snyA[rowi] + syj - 2.f * accY[m][n][r];
                float dyv = sqrtf(fmaxf(d2y, 1e-12f));
                int gi = iA + rowi, gj = iB + col;
                bool keep = (gi != gj) && (dxv <= EPS_THR);
                float contrib = __expf(-dxv * SIGMA_INV) * dyv;
                local += keep ? contrib : 0.f;
            }
        }
    }
    if (bi != bj) local *= 2.f;

#pragma unroll
    for (int off = 32; off > 0; off >>= 1)
        local += __shfl_down(local, off, 64);
    if (lane == 0) wsum[wid] = local;
    __syncthreads();
    if (tid == 0)
        atomicAdd(out, wsum[0] + wsum[1] + wsum[2] + wsum[3]);
}

// ===========================================================================
extern "C" void kernel_launch(void* const* d_in, const int* in_sizes, int n_in,
                              void* d_out, int out_size, void* d_ws, size_t ws_size,
                              hipStream_t stream) {
    const float* x = (const float*)d_in[0];
    const float* y = (const float*)d_in[1];
    float* out = (float*)d_out;

    hipMemsetAsync(d_out, 0, sizeof(float) * (size_t)out_size, stream);

    const size_t xb_bytes = (size_t)BATCH * XSLOTS * 16;   // 8 MB
    const size_t yb_bytes = (size_t)BATCH * YSLOTS * 16;   // 4 MB
    const size_t need = xb_bytes + yb_bytes + 2 * (size_t)BATCH * sizeof(float);

    if (ws_size >= need) {
        u16x8* xb  = (u16x8*)d_ws;
        u16x8* yb  = (u16x8*)((char*)d_ws + xb_bytes);
        float* sqx = (float*)((char*)d_ws + xb_bytes + yb_bytes);
        float* sqy = sqx + BATCH;
        convert_kernel<<<BATCH, 192, 0, stream>>>(x, y, xb, yb, sqx, sqy);
        graph_loss_bf16<<<NBLK, 256, 0, stream>>>(xb, yb, sqx, sqy, out);
    } else {
        float* sqx = (float*)d_ws;
        float* sqy = sqx + BATCH;
        norms_kernel_fb<<<BATCH, 64, 0, stream>>>(x, y, sqx, sqy);
        graph_loss_fb<<<NBLK, 256, 0, stream>>>(x, y, sqx, sqy, out);
    }
}

// Round 6
// 71.876 us; speedup vs baseline: 2.6902x; 1.0229x over previous
//
#include <hip/hip_runtime.h>
#include <hip/hip_bf16.h>
#include <stdint.h>

// Problem constants (from reference)
#define BATCH 4096
#define D_X   1024
#define D_Y   512

constexpr float SIGMA_INV = 0.1f;    // 1/10.0
constexpr float EPS_THR   = 46.0f;

constexpr int BM = 128;              // tile M = tile N
constexpr int NT = BATCH / BM;       // 32 tile-rows
constexpr int NBLK = NT * (NT + 1) / 2;  // 528 upper-triangular tiles (528%8==0)

constexpr int XSLOTS = D_X / 8;      // 128 16B-slots (8 bf16) per x row
constexpr int YSLOTS = D_Y / 8;      // 64 slots per y row
constexpr int NSTEPX = D_X / 32;     // 32 X K-steps (BK=32)
constexpr int NSTEP  = NSTEPX + D_Y / 32;  // 48 total K-steps

typedef __bf16 bf16x8 __attribute__((ext_vector_type(8)));
typedef float  f32x4  __attribute__((ext_vector_type(4)));
typedef unsigned short u16x8 __attribute__((ext_vector_type(8)));

__device__ __forceinline__ unsigned short f32_to_bf16_bits(float f) {
    unsigned int u = __builtin_bit_cast(unsigned int, f);
    unsigned int r = (u + 0x7FFFu + ((u >> 16) & 1u)) >> 16;  // RNE
    return (unsigned short)r;
}

// ===========================================================================
// FAST PATH
// ===========================================================================

// ---------------------------------------------------------------------------
// Kernel 1: f32 -> bf16 (LINEAR slot layout) + row norms.
// ---------------------------------------------------------------------------
__global__ void __launch_bounds__(192)
convert_kernel(const float* __restrict__ x, const float* __restrict__ y,
               u16x8* __restrict__ xb, u16x8* __restrict__ yb,
               float* __restrict__ sqx, float* __restrict__ sqy) {
    __shared__ float part[2];
    const int row = blockIdx.x;
    const int t   = threadIdx.x;
    const int lane = t & 63;
    const int wid  = t >> 6;

    float ss = 0.f;
    if (t < 128) {
        const float4* p = (const float4*)(x + (size_t)row * D_X + t * 8);
        float4 a = p[0], b = p[1];
        ss = a.x*a.x + a.y*a.y + a.z*a.z + a.w*a.w
           + b.x*b.x + b.y*b.y + b.z*b.z + b.w*b.w;
        u16x8 v;
        v[0] = f32_to_bf16_bits(a.x); v[1] = f32_to_bf16_bits(a.y);
        v[2] = f32_to_bf16_bits(a.z); v[3] = f32_to_bf16_bits(a.w);
        v[4] = f32_to_bf16_bits(b.x); v[5] = f32_to_bf16_bits(b.y);
        v[6] = f32_to_bf16_bits(b.z); v[7] = f32_to_bf16_bits(b.w);
        xb[(size_t)row * XSLOTS + t] = v;
    } else {
        int o = t - 128;  // 0..63
        const float4* p = (const float4*)(y + (size_t)row * D_Y + o * 8);
        float4 a = p[0], b = p[1];
        ss = a.x*a.x + a.y*a.y + a.z*a.z + a.w*a.w
           + b.x*b.x + b.y*b.y + b.z*b.z + b.w*b.w;
        u16x8 v;
        v[0] = f32_to_bf16_bits(a.x); v[1] = f32_to_bf16_bits(a.y);
        v[2] = f32_to_bf16_bits(a.z); v[3] = f32_to_bf16_bits(a.w);
        v[4] = f32_to_bf16_bits(b.x); v[5] = f32_to_bf16_bits(b.y);
        v[6] = f32_to_bf16_bits(b.z); v[7] = f32_to_bf16_bits(b.w);
        yb[(size_t)row * YSLOTS + o] = v;
    }
#pragma unroll
    for (int off = 32; off > 0; off >>= 1)
        ss += __shfl_down(ss, off, 64);
    if (lane == 0) {
        if (wid < 2) part[wid] = ss;
        else         sqy[row] = ss;
    }
    __syncthreads();
    if (t == 0) sqx[row] = part[0] + part[1];
}

// ---------------------------------------------------------------------------
// Issue one K=32 step's staging: [128 rows][8 slots] combined A|B tile, 16 KB.
// Stored slot st of row r holds: logical lg = st ^ (r&7);  lg<4 -> A slot
// (k0+lg) of row iA+r,  lg>=4 -> B slot (k0+lg-4) of row iB+r.
// LDS dest LINEAR; swizzle lives in the per-lane GLOBAL source (rule #21).
// 4 global_load_lds per thread -> 4 vmcnt units per step batch.
// ---------------------------------------------------------------------------
__device__ __forceinline__ void issue_stage(int s,
                                            const u16x8* __restrict__ xb,
                                            const u16x8* __restrict__ yb,
                                            int iA, int iB,
                                            u16x8* dst, int tid) {
    const int wid = tid >> 6, lane = tid & 63;
    const u16x8* src; int rs, k0;
    if (s < NSTEPX) { src = xb; rs = XSLOTS; k0 = s * 4; }
    else            { src = yb; rs = YSLOTS; k0 = (s - NSTEPX) * 4; }
#pragma unroll
    for (int it = 0; it < 4; ++it) {
        int u   = it * 256 + wid * 64;   // wave-uniform LDS slot base
        int ul  = u + lane;
        int row = ul >> 3;
        int st  = ul & 7;
        int lg  = st ^ (row & 7);
        int grow  = (lg < 4 ? iA : iB) + row;
        int gslot = k0 + (lg & 3);
        const u16x8* g = src + (size_t)grow * rs + gslot;
        __builtin_amdgcn_global_load_lds(
            (const uint32_t __attribute__((address_space(1)))*)g,
            (uint32_t __attribute__((address_space(3)))*)(dst + u), 16, 0, 0);
    }
}

// Read the 8 fragments of one K=32 step (A logical slots 0-3, B slots 4-7).
__device__ __forceinline__ void read_frags32(const u16x8* B_, int wr, int wc,
                                             int lrow, int kgrp,
                                             bf16x8 a[4], bf16x8 b[4]) {
#pragma unroll
    for (int m = 0; m < 4; ++m) {
        int row = wr * 64 + m * 16 + lrow;
        int st  = kgrp ^ (row & 7);
        a[m] = __builtin_bit_cast(bf16x8, B_[row * 8 + st]);
    }
#pragma unroll
    for (int n = 0; n < 4; ++n) {
        int row = wc * 64 + n * 16 + lrow;
        int st  = (4 + kgrp) ^ (row & 7);
        b[n] = __builtin_bit_cast(bf16x8, B_[row * 8 + st]);
    }
}

__device__ __forceinline__ void mfma16(const bf16x8 a[4], const bf16x8 b[4],
                                       f32x4 acc[4][4]) {
#pragma unroll
    for (int m = 0; m < 4; ++m)
#pragma unroll
        for (int n = 0; n < 4; ++n)
            acc[m][n] = __builtin_amdgcn_mfma_f32_16x16x32_bf16(
                a[m], b[n], acc[m][n], 0, 0, 0);
}

// One pipeline step (depth-2): counted vmcnt (NEVER 0 in steady state) +
// raw barrier. RD = buffer of step T; WR = buffer for step T+2's staging.
// T5: setprio(1) around the MFMA cluster (cross-block role diversity).
#define PIPE_STEP(RD, T, WR, ACC, W)                                      \
    {                                                                     \
        asm volatile("s_waitcnt vmcnt(" #W ")" ::: "memory");             \
        __builtin_amdgcn_s_barrier();                                     \
        bf16x8 fa[4], fb[4];                                              \
        read_frags32(RD, wr, wc, lrow, kgrp, fa, fb);                     \
        issue_stage((T) + 2, xb, yb, iA, iB, WR, tid);                    \
        __builtin_amdgcn_s_setprio(1);                                    \
        mfma16(fa, fb, ACC);                                              \
        __builtin_amdgcn_s_setprio(0);                                    \
    }
#define PIPE_STEP_NOISSUE(RD, ACC, W)                                     \
    {                                                                     \
        asm volatile("s_waitcnt vmcnt(" #W ")" ::: "memory");             \
        __builtin_amdgcn_s_barrier();                                     \
        bf16x8 fa[4], fb[4];                                              \
        read_frags32(RD, wr, wc, lrow, kgrp, fa, fb);                     \
        __builtin_amdgcn_s_setprio(1);                                    \
        mfma16(fa, fb, ACC);                                              \
        __builtin_amdgcn_s_setprio(0);                                    \
    }

// ---------------------------------------------------------------------------
// Kernel 2: fused Gram(x), Gram(y) -> masked heat-kernel loss.
// Depth-2 pipeline, 3 cyclic 16KB buffers (~51KB LDS -> 3 blocks/CU, ALL
// 528 blocks co-resident -> no sequential tail), counted vmcnt(4).
// ---------------------------------------------------------------------------
__global__ void __launch_bounds__(256, 3)
graph_loss_bf16(const u16x8* __restrict__ xb, const u16x8* __restrict__ yb,
                const float* __restrict__ sqx, const float* __restrict__ sqy,
                float* __restrict__ out) {
    __shared__ u16x8 buf0[1024], buf1[1024], buf2[1024];  // 48 KB
    __shared__ float snxA[BM], snxB[BM], snyA[BM], snyB[BM];
    __shared__ float wsum[4];

    const int tid  = threadIdx.x;
    const int lane = tid & 63;
    const int wid  = tid >> 6;
    const int wr   = wid >> 1;
    const int wc   = wid & 1;
    const int lrow = lane & 15;
    const int kgrp = lane >> 4;

    // T1: chunked XCD swizzle (bijective: NBLK % 8 == 0).
    int sb = (blockIdx.x & 7) * (NBLK / 8) + (blockIdx.x >> 3);

    // triangular tile mapping
    int t0 = sb, bi = 0;
    while (t0 >= NT - bi) { t0 -= NT - bi; ++bi; }
    const int bj = bi + t0;
    const int iA = bi * BM;
    const int iB = bj * BM;
    const bool diag = (bi == bj);

    if (tid < BM) {
        snxA[tid] = sqx[iA + tid];
        snyA[tid] = sqy[iA + tid];
        snxB[tid] = sqx[iB + tid];
        snyB[tid] = sqy[iB + tid];
    }

    f32x4 accX[4][4] = {};
    f32x4 accY[4][4] = {};

    // ---- prologue: pre-issue steps 0,1 (8 loads in flight) ----
    issue_stage(0, xb, yb, iA, iB, buf0, tid);
    issue_stage(1, xb, yb, iA, iB, buf1, tid);

    // ---- X phase: steps 0..29 ----
    for (int g = 0; g < 10; ++g) {
        int t = g * 3;
        PIPE_STEP(buf0, t + 0, buf2, accX, 4);
        PIPE_STEP(buf1, t + 1, buf0, accX, 4);
        PIPE_STEP(buf2, t + 2, buf1, accX, 4);
    }
    // ---- mixed group: steps 30,31 (X), 32 (Y) ----
    PIPE_STEP(buf0, 30, buf2, accX, 4);
    PIPE_STEP(buf1, 31, buf0, accX, 4);
    PIPE_STEP(buf2, 32, buf1, accY, 4);
    // ---- Y phase: steps 33..44 ----
    for (int g = 11; g < 15; ++g) {
        int t = g * 3;
        PIPE_STEP(buf0, t + 0, buf2, accY, 4);
        PIPE_STEP(buf1, t + 1, buf0, accY, 4);
        PIPE_STEP(buf2, t + 2, buf1, accY, 4);
    }
    // ---- peeled tail: steps 45,46,47 ----
    PIPE_STEP(buf0, 45, buf2, accY, 4);   // issues step 47
    PIPE_STEP_NOISSUE(buf1, accY, 4);     // step 46 (47's batch in flight)
    PIPE_STEP_NOISSUE(buf2, accY, 0);     // step 47 (full drain)

    // ---- Epilogue: C/D layout col=lane&15, row=(lane>>4)*4+reg (m89) ----
    float local = 0.f;
#pragma unroll
    for (int m = 0; m < 4; ++m) {
#pragma unroll
        for (int n = 0; n < 4; ++n) {
            int col   = wc * 64 + n * 16 + lrow;
            float sxj = snxB[col];
            float syj = snyB[col];
#pragma unroll
            for (int r = 0; r < 4; ++r) {
                int rowi  = wr * 64 + m * 16 + kgrp * 4 + r;
                float d2x = snxA[rowi] + sxj - 2.f * accX[m][n][r];
                float dxv = sqrtf(fmaxf(d2x, 1e-12f));
                float d2y = snyA[rowi] + syj - 2.f * accY[m][n][r];
                float dyv = sqrtf(fmaxf(d2y, 1e-12f));
                int gi = iA + rowi, gj = iB + col;
                bool keep = (gi != gj) && (dxv <= EPS_THR);
                float contrib = __expf(-dxv * SIGMA_INV) * dyv;
                local += keep ? contrib : 0.f;
            }
        }
    }
    if (!diag) local *= 2.f;

#pragma unroll
    for (int off = 32; off > 0; off >>= 1)
        local += __shfl_down(local, off, 64);
    if (lane == 0) wsum[wid] = local;
    __syncthreads();
    if (tid == 0)
        atomicAdd(out, wsum[0] + wsum[1] + wsum[2] + wsum[3]);
}

// ===========================================================================
// FALLBACK PATH (used only if ws_size is too small) — round-2 structure.
// ===========================================================================
__global__ void norms_kernel_fb(const float* __restrict__ x,
                                const float* __restrict__ y,
                                float* __restrict__ sqx,
                                float* __restrict__ sqy) {
    int row = blockIdx.x;
    int t   = threadIdx.x;
    const float4* xr = (const float4*)(x + (size_t)row * D_X);
    float sx = 0.f;
#pragma unroll
    for (int i = 0; i < D_X / 4 / 64; ++i) {
        float4 v = xr[t + i * 64];
        sx += v.x * v.x + v.y * v.y + v.z * v.z + v.w * v.w;
    }
    const float4* yr = (const float4*)(y + (size_t)row * D_Y);
    float sy = 0.f;
#pragma unroll
    for (int i = 0; i < D_Y / 4 / 64; ++i) {
        float4 v = yr[t + i * 64];
        sy += v.x * v.x + v.y * v.y + v.z * v.z + v.w * v.w;
    }
#pragma unroll
    for (int off = 32; off > 0; off >>= 1) {
        sx += __shfl_down(sx, off, 64);
        sy += __shfl_down(sy, off, 64);
    }
    if (t == 0) { sqx[row] = sx; sqy[row] = sy; }
}

__device__ __forceinline__ void stage_tile_fb(const float* __restrict__ src, int ld,
                                              int base_row, int k0,
                                              u16x8* __restrict__ dst, int tid) {
#pragma unroll
    for (int it = 0; it < 2; ++it) {
        int u   = tid + it * 256;
        int row = u >> 2;
        int q   = u & 3;
        const float4* p = (const float4*)(src + (size_t)(base_row + row) * ld + k0 + q * 16);
        float4 f0 = p[0], f1 = p[1], f2 = p[2], f3 = p[3];
        u16x8 lo, hi;
        lo[0] = f32_to_bf16_bits(f0.x); lo[1] = f32_to_bf16_bits(f0.y);
        lo[2] = f32_to_bf16_bits(f0.z); lo[3] = f32_to_bf16_bits(f0.w);
        lo[4] = f32_to_bf16_bits(f1.x); lo[5] = f32_to_bf16_bits(f1.y);
        lo[6] = f32_to_bf16_bits(f1.z); lo[7] = f32_to_bf16_bits(f1.w);
        hi[0] = f32_to_bf16_bits(f2.x); hi[1] = f32_to_bf16_bits(f2.y);
        hi[2] = f32_to_bf16_bits(f2.z); hi[3] = f32_to_bf16_bits(f2.w);
        hi[4] = f32_to_bf16_bits(f3.x); hi[5] = f32_to_bf16_bits(f3.y);
        hi[6] = f32_to_bf16_bits(f3.z); hi[7] = f32_to_bf16_bits(f3.w);
        int swz = row & 7;
        dst[row * 8 + ((2 * q) ^ swz)]     = lo;
        dst[row * 8 + ((2 * q + 1) ^ swz)] = hi;
    }
}

__device__ __forceinline__ void load_frags_fb(const u16x8* As_, const u16x8* Bs_,
                                              int wr, int wc, int lrow, int kgrp,
                                              bf16x8 a[2][4], bf16x8 b[2][4]) {
#pragma unroll
    for (int ks = 0; ks < 2; ++ks) {
#pragma unroll
        for (int m = 0; m < 4; ++m) {
            int row  = wr * 64 + m * 16 + lrow;
            int slot = (ks * 4 + kgrp) ^ (row & 7);
            a[ks][m] = __builtin_bit_cast(bf16x8, As_[row * 8 + slot]);
        }
#pragma unroll
        for (int n = 0; n < 4; ++n) {
            int row  = wc * 64 + n * 16 + lrow;
            int slot = (ks * 4 + kgrp) ^ (row & 7);
            b[ks][n] = __builtin_bit_cast(bf16x8, Bs_[row * 8 + slot]);
        }
    }
}

__global__ void __launch_bounds__(256, 2)
graph_loss_fb(const float* __restrict__ x, const float* __restrict__ y,
              const float* __restrict__ sqx, const float* __restrict__ sqy,
              float* __restrict__ out) {
    __shared__ u16x8 As[BM * 8];
    __shared__ u16x8 Bs[BM * 8];
    __shared__ float snxA[BM], snxB[BM], snyA[BM], snyB[BM];
    __shared__ float wsum[4];

    const int tid  = threadIdx.x;
    const int lane = tid & 63;
    const int wid  = tid >> 6;
    const int wr   = wid >> 1;
    const int wc   = wid & 1;
    const int lrow = lane & 15;
    const int kgrp = lane >> 4;

    int t = blockIdx.x, bi = 0;
    while (t >= NT - bi) { t -= NT - bi; ++bi; }
    const int bj = bi + t;
    const int iA = bi * BM;
    const int iB = bj * BM;

    if (tid < BM) {
        snxA[tid] = sqx[iA + tid];
        snyA[tid] = sqy[iA + tid];
        snxB[tid] = sqx[iB + tid];
        snyB[tid] = sqy[iB + tid];
    }

    f32x4 accX[4][4] = {};
    f32x4 accY[4][4] = {};
    bf16x8 a[2][4], b[2][4];

    for (int kt = 0; kt < D_X / 64; ++kt) {
        __syncthreads();
        stage_tile_fb(x, D_X, iA, kt * 64, As, tid);
        stage_tile_fb(x, D_X, iB, kt * 64, Bs, tid);
        __syncthreads();
        load_frags_fb(As, Bs, wr, wc, lrow, kgrp, a, b);
#pragma unroll
        for (int ks = 0; ks < 2; ++ks) mfma16(a[ks], b[ks], accX);
    }
    for (int kt = 0; kt < D_Y / 64; ++kt) {
        __syncthreads();
        stage_tile_fb(y, D_Y, iA, kt * 64, As, tid);
        stage_tile_fb(y, D_Y, iB, kt * 64, Bs, tid);
        __syncthreads();
        load_frags_fb(As, Bs, wr, wc, lrow, kgrp, a, b);
#pragma unroll
        for (int ks = 0; ks < 2; ++ks) mfma16(a[ks], b[ks], accY);
    }

    float local = 0.f;
#pragma unroll
    for (int m = 0; m < 4; ++m) {
#pragma unroll
        for (int n = 0; n < 4; ++n) {
            int col   = wc * 64 + n * 16 + lrow;
            float sxj = snxB[col];
            float syj = snyB[col];
#pragma unroll
            for (int r = 0; r < 4; ++r) {
                int rowi  = wr * 64 + m * 16 + kgrp * 4 + r;
                float d2x = snxA[rowi] + sxj - 2.f * accX[m][n][r];
                float dxv = sqrtf(fmaxf(d2x, 1e-12f));
                float d2y = snyA[rowi] + syj - 2.f * accY[m][n][r];
                float dyv = sqrtf(fmaxf(d2y, 1e-12f));
                int gi = iA + rowi, gj = iB + col;
                bool keep = (gi != gj) && (dxv <= EPS_THR);
                float contrib = __expf(-dxv * SIGMA_INV) * dyv;
                local += keep ? contrib : 0.f;
            }
        }
    }
    if (bi != bj) local *= 2.f;

#pragma unroll
    for (int off = 32; off > 0; off >>= 1)
        local += __shfl_down(local, off, 64);
    if (lane == 0) wsum[wid] = local;
    __syncthreads();
    if (tid == 0)
        atomicAdd(out, wsum[0] + wsum[1] + wsum[2] + wsum[3]);
}

// ===========================================================================
extern "C" void kernel_launch(void* const* d_in, const int* in_sizes, int n_in,
                              void* d_out, int out_size, void* d_ws, size_t ws_size,
                              hipStream_t stream) {
    const float* x = (const float*)d_in[0];
    const float* y = (const float*)d_in[1];
    float* out = (float*)d_out;

    hipMemsetAsync(d_out, 0, sizeof(float) * (size_t)out_size, stream);

    const size_t xb_bytes = (size_t)BATCH * XSLOTS * 16;   // 8 MB
    const size_t yb_bytes = (size_t)BATCH * YSLOTS * 16;   // 4 MB
    const size_t need = xb_bytes + yb_bytes + 2 * (size_t)BATCH * sizeof(float);

    if (ws_size >= need) {
        u16x8* xb  = (u16x8*)d_ws;
        u16x8* yb  = (u16x8*)((char*)d_ws + xb_bytes);
        float* sqx = (float*)((char*)d_ws + xb_bytes + yb_bytes);
        float* sqy = sqx + BATCH;
        convert_kernel<<<BATCH, 192, 0, stream>>>(x, y, xb, yb, sqx, sqy);
        graph_loss_bf16<<<NBLK, 256, 0, stream>>>(xb, yb, sqx, sqy, out);
    } else {
        float* sqx = (float*)d_ws;
        float* sqy = sqx + BATCH;
        norms_kernel_fb<<<BATCH, 64, 0, stream>>>(x, y, sqx, sqy);
        graph_loss_fb<<<NBLK, 256, 0, stream>>>(x, y, sqx, sqy, out);
    }
}